// Round 6
// baseline (394.523 us; speedup 1.0000x reference)
//
#include <hip/hip_runtime.h>
#include <hip/hip_bf16.h>
#include <stdint.h>

#define B_ 256
#define H_ 4096
#define K_ 32768   // V*N = 1024*32

typedef __attribute__((ext_vector_type(8))) short bf16x8;
typedef __attribute__((ext_vector_type(4))) float f32x4;

__device__ __forceinline__ unsigned short f2bf(float x) {
    union { float f; unsigned int u; } c; c.f = x;
    unsigned int r = c.u + 0x7FFFu + ((c.u >> 16) & 1u);  // RNE
    return (unsigned short)(r >> 16);
}

__device__ __forceinline__ short bfc(float x) {
    __hip_bfloat16 h = __float2bfloat16(x);
    union { __hip_bfloat16 h; short s; } c; c.h = h;
    return c.s;
}

__device__ __forceinline__ float softplus_f(float x) {
    return fmaxf(x, 0.0f) + log1pf(expf(-fabsf(x)));
}

// ---------------- Kernel A: v fp32->bf16 + vt[b] = dot(v[b,:], b_v) ----------------
__global__ __launch_bounds__(256) void prep_kernel(
    const float* __restrict__ v, const float* __restrict__ bv,
    __hip_bfloat16* __restrict__ vbf, float* __restrict__ vt)
{
    const int b = blockIdx.x;
    const int t = threadIdx.x;
    const float* vr = v + (size_t)b * K_;
    unsigned short* dr = (unsigned short*)(vbf + (size_t)b * K_);
    float acc = 0.f;
    for (int i = t * 8; i < K_; i += 256 * 8) {
        float4 x0 = *(const float4*)(vr + i);
        float4 x1 = *(const float4*)(vr + i + 4);
        float4 b0 = *(const float4*)(bv + i);
        float4 b1 = *(const float4*)(bv + i + 4);
        acc += x0.x*b0.x + x0.y*b0.y + x0.z*b0.z + x0.w*b0.w
             + x1.x*b1.x + x1.y*b1.y + x1.z*b1.z + x1.w*b1.w;
        ushort4 u0, u1;
        u0.x = f2bf(x0.x); u0.y = f2bf(x0.y); u0.z = f2bf(x0.z); u0.w = f2bf(x0.w);
        u1.x = f2bf(x1.x); u1.y = f2bf(x1.y); u1.z = f2bf(x1.z); u1.w = f2bf(x1.w);
        *(ushort4*)(dr + i)     = u0;
        *(ushort4*)(dr + i + 4) = u1;
    }
    __shared__ float sm[256];
    sm[t] = acc;
    __syncthreads();
    for (int s = 128; s > 0; s >>= 1) {
        if (t < s) sm[t] += sm[t + s];
        __syncthreads();
    }
    if (t == 0) vt[b] = sm[0];
}

// ---------------- Kernel B: split-K GEMM, BM=256 BN=64 BK=64 ----------------
// R3 structure (depth-4 LDS ring for W fp32 via global_load_lds, XOR-swizzled;
// A direct global->reg double-buffered; ONE fused {s_waitcnt; s_barrier} per
// K-step, counted vmcnt never 0 in main loop) with waves re-shaped 4M x 2N:
// each wave = 64 rows x 32 cols -> reads only HALF the W tile from LDS
// (8 ds_read_b128/body instead of 16) and does half the cvt VALU. A-loads
// double (8/body) but come from the XCD-pinned L2-resident v slice.
//
// Per-wave vmem FIFO (per body: A(t+1)=8 loads, W(t+2)=2 gl_lds):
//   at BODY(t) wait: W(t)2 A(t)8 W(t+1)2 A(t+1)8 W(t+2)2 = 22
//   vmcnt(12) frees oldest 10 = W(t)+A(t); keeps W(t+1),A(t+1),W(t+2).
//   Tail: BODY(NT-2) -> vmcnt(10); BODY(NT-1) -> vmcnt(0).
// Ring: writes target slot (t+2)&3, laggard reads slots t&3/(t+1)&3 -> disjoint.

#define STAGE_W(slot, kt) do {                                                         \
    _Pragma("unroll")                                                                  \
    for (int p_ = 0; p_ < 2; ++p_) {                                                   \
        __builtin_amdgcn_global_load_lds(                                              \
            (const __attribute__((address_space(1))) unsigned int*)(wsrc[p_] + (size_t)(kt) * 64), \
            (__attribute__((address_space(3))) unsigned int*)(&wbuf[(slot)][wldsoff[p_]]), \
            16, 0, 0);                                                                 \
    } } while (0)

#define LOAD_A(dst, kt) do {                                                           \
    _Pragma("unroll")                                                                  \
    for (int m_ = 0; m_ < 4; ++m_)                                                     \
      _Pragma("unroll")                                                                \
      for (int s_ = 0; s_ < 2; ++s_)                                                   \
        dst[m_*2+s_] = *(const bf16x8*)(ap[m_] + (size_t)(kt) * 64 + s_ * 32);         \
    } while (0)

#define COMPUTE(AUSE, T_) do {                                                         \
    const float* wb_ = &wbuf[(T_) & 3][0];                                             \
    _Pragma("unroll")                                                                  \
    for (int s_ = 0; s_ < 2; ++s_) {                                                   \
      bf16x8 bfr[2];                                                                   \
      _Pragma("unroll")                                                                \
      for (int n_ = 0; n_ < 2; ++n_) {                                                 \
        int row_ = wn * 32 + n_ * 16 + lr;                                             \
        int m7_  = row_ & 7;                                                           \
        int g0_  = s_ * 8 + lg * 2;                                                    \
        float4 lo_ = *(const float4*)&wb_[row_ * 64 + (((g0_    ) ^ m7_) << 2)];       \
        float4 hi_ = *(const float4*)&wb_[row_ * 64 + (((g0_ + 1) ^ m7_) << 2)];       \
        bf16x8 t_;                                                                     \
        t_[0]=bfc(lo_.x); t_[1]=bfc(lo_.y); t_[2]=bfc(lo_.z); t_[3]=bfc(lo_.w);        \
        t_[4]=bfc(hi_.x); t_[5]=bfc(hi_.y); t_[6]=bfc(hi_.z); t_[7]=bfc(hi_.w);        \
        bfr[n_] = t_;                                                                  \
      }                                                                                \
      _Pragma("unroll")                                                                \
      for (int m_ = 0; m_ < 4; ++m_)                                                   \
        _Pragma("unroll")                                                              \
        for (int n_ = 0; n_ < 2; ++n_)                                                 \
          acc[m_][n_] = __builtin_amdgcn_mfma_f32_16x16x32_bf16(                       \
              AUSE[m_*2+s_], bfr[n_], acc[m_][n_], 0, 0, 0);                           \
    } } while (0)

// Fused wait+barrier in ONE asm: nothing can be scheduled between or across.
#define WAIT_BAR(VMSTR) \
    asm volatile("s_waitcnt " VMSTR "\n\ts_barrier" ::: "memory")

#define BODY(T_, AUSE, ALOAD, ISSW, ISSA, VMSTR) do {                                  \
    if (ISSA) LOAD_A(ALOAD, (T_) + 1);                                                 \
    if (ISSW) STAGE_W(((T_) + 2) & 3, (T_) + 2);                                       \
    WAIT_BAR(VMSTR);                                                                   \
    COMPUTE(AUSE, T_);                                                                 \
    } while (0)

__global__ __launch_bounds__(512, 4) void gemm_kernel(
    const __hip_bfloat16* __restrict__ vbf,   // [256][32768] bf16
    const float* __restrict__ W,              // [4096][32768] fp32
    float* __restrict__ part,                 // [KS][256][4096] fp32
    int KS, int NT)                           // NT = (K_/KS)/64, even, >= 4
{
    __shared__ __align__(16) float wbuf[4][64 * 64];   // 4 x 16 KB ring

    const int tid  = threadIdx.x;
    const int wid  = tid >> 6;
    const int lane = tid & 63;
    const int lr   = lane & 15;   // B-frag n / A-frag row-in-16
    const int lg   = lane >> 4;   // k-granule 0..3

    const int wm = wid & 3;       // wave M group: 64 rows
    const int wn = wid >> 2;      // wave N group: 32 cols

    const int bid   = blockIdx.x;
    const int sidx  = bid % KS;   // k-split; == XCD id when KS==8 (v-slice L2 locality)
    const int ht    = bid / KS;
    const int h0    = ht * 64;
    const int kbase = sidx * (NT * 64);

    // W staging: LDS linear granule (row, g') holds global granule g = g' ^ (row&7)
    const float* wsrc[2];
    int wldsoff[2];
    #pragma unroll
    for (int p = 0; p < 2; ++p) {
        int f   = p * 512 + tid;
        int row = f >> 4;       // 0..63
        int gl  = f & 15;       // linear 16B granule in row
        int g   = gl ^ (row & 7);
        wsrc[p]    = W + (size_t)(h0 + row) * K_ + kbase + g * 4;
        wldsoff[p] = (p * 512 + wid * 64) * 4;   // float idx, wave-uniform base
    }

    // A: this wave owns rows wm*64 .. wm*64+63
    const __hip_bfloat16* ap[4];
    #pragma unroll
    for (int m = 0; m < 4; ++m)
        ap[m] = vbf + (size_t)(wm * 64 + m * 16 + lr) * K_ + kbase + lg * 8;

    f32x4 acc[4][2];
    #pragma unroll
    for (int m = 0; m < 4; ++m)
        #pragma unroll
        for (int n = 0; n < 2; ++n)
            acc[m][n] = (f32x4)(0.0f);

    bf16x8 aA[8], aB[8];

    // Prologue: A(0), W(0), W(1); fence so BODY(0)'s issues can't interleave in.
    LOAD_A(aA, 0);
    STAGE_W(0, 0);
    STAGE_W(1, 1);
    asm volatile("" ::: "memory");

    for (int t = 0; t < NT - 2; t += 2) {
        BODY(t,     aA, aB, true, true, "vmcnt(12)");
        BODY(t + 1, aB, aA, true, true, "vmcnt(12)");
    }
    BODY(NT - 2, aA, aB, false, true,  "vmcnt(10)");
    BODY(NT - 1, aB, aA, false, false, "vmcnt(0)");

    // Epilogue: C/D layout col=lane&15 (=h), row=(lane>>4)*4+reg (=b)
    float* pout = part + (size_t)sidx * ((size_t)B_ * H_) + h0;
    #pragma unroll
    for (int m = 0; m < 4; ++m)
        #pragma unroll
        for (int n = 0; n < 2; ++n)
            #pragma unroll
            for (int j = 0; j < 4; ++j) {
                int brow = wm * 64 + m * 16 + lg * 4 + j;
                int hcol = wn * 32 + n * 16 + lr;
                pout[(size_t)brow * H_ + hcol] = acc[m][n][j];
            }
}

// ---------------- Kernel C: reduce splits + b_h, softplus, sum over H, + vt ----------------
__global__ __launch_bounds__(256) void reduce_kernel(
    const float* __restrict__ part, const float* __restrict__ bh,
    const float* __restrict__ vt, float* __restrict__ out, int KS)
{
    const int b = blockIdx.x;
    const int t = threadIdx.x;
    float sp = 0.f;
    const float* pb = part + (size_t)b * H_;
    for (int h = t * 4; h < H_; h += 256 * 4) {
        float4 l = *(const float4*)(bh + h);
        for (int s = 0; s < KS; ++s) {
            float4 p = *(const float4*)(pb + (size_t)s * B_ * H_ + h);
            l.x += p.x; l.y += p.y; l.z += p.z; l.w += p.w;
        }
        sp += softplus_f(l.x) + softplus_f(l.y) + softplus_f(l.z) + softplus_f(l.w);
    }
    __shared__ float sm[256];
    sm[t] = sp;
    __syncthreads();
    for (int r = 128; r > 0; r >>= 1) {
        if (t < r) sm[t] += sm[t + r];
        __syncthreads();
    }
    if (t == 0) out[b] = sm[0] + vt[b];
}

extern "C" void kernel_launch(void* const* d_in, const int* in_sizes, int n_in,
                              void* d_out, int out_size, void* d_ws, size_t ws_size,
                              hipStream_t stream)
{
    const float* v  = (const float*)d_in[0];
    const float* W  = (const float*)d_in[1];
    const float* bh = (const float*)d_in[2];
    const float* bv = (const float*)d_in[3];
    float* out = (float*)d_out;

    char* ws = (char*)d_ws;
    const size_t vbf_bytes = (size_t)B_ * K_ * sizeof(__hip_bfloat16);  // 16 MB
    __hip_bfloat16* vbf = (__hip_bfloat16*)ws;

    int KS = 8;                                   // shrink if workspace is small
    while (KS > 1 && vbf_bytes + (size_t)KS * B_ * H_ * 4 + 1024 > ws_size) KS >>= 1;

    float* part = (float*)(ws + vbf_bytes);                                  // KS*4 MB
    float* vt   = (float*)(ws + vbf_bytes + (size_t)KS * B_ * H_ * 4);       // 1 KB

    prep_kernel<<<B_, 256, 0, stream>>>(v, bv, vbf, vt);
    const int NT = (K_ / KS) / 64;                // 64 for KS=8 (even, >=4)
    gemm_kernel<<<(H_ / 64) * KS, 512, 0, stream>>>(vbf, W, part, KS, NT);
    reduce_kernel<<<B_, 256, 0, stream>>>(part, bh, vt, out, KS);
}

// Round 7
// 318.733 us; speedup vs baseline: 1.2378x; 1.2378x over previous
//
#include <hip/hip_runtime.h>
#include <hip/hip_bf16.h>
#include <stdint.h>

#define B_ 256
#define H_ 4096
#define K_ 32768   // V*N = 1024*32

typedef __attribute__((ext_vector_type(8))) short bf16x8;
typedef __attribute__((ext_vector_type(4))) float f32x4;

__device__ __forceinline__ unsigned short f2bf(float x) {
    union { float f; unsigned int u; } c; c.f = x;
    unsigned int r = c.u + 0x7FFFu + ((c.u >> 16) & 1u);  // RNE
    return (unsigned short)(r >> 16);
}

__device__ __forceinline__ short bfc(float x) {
    __hip_bfloat16 h = __float2bfloat16(x);
    union { __hip_bfloat16 h; short s; } c; c.h = h;
    return c.s;
}

__device__ __forceinline__ float softplus_f(float x) {
    return fmaxf(x, 0.0f) + log1pf(expf(-fabsf(x)));
}

// ---------------- Kernel A: v fp32->bf16 + vt[b] = dot(v[b,:], b_v) ----------------
__global__ __launch_bounds__(256) void prep_kernel(
    const float* __restrict__ v, const float* __restrict__ bv,
    __hip_bfloat16* __restrict__ vbf, float* __restrict__ vt)
{
    const int b = blockIdx.x;
    const int t = threadIdx.x;
    const float* vr = v + (size_t)b * K_;
    unsigned short* dr = (unsigned short*)(vbf + (size_t)b * K_);
    float acc = 0.f;
    for (int i = t * 8; i < K_; i += 256 * 8) {
        float4 x0 = *(const float4*)(vr + i);
        float4 x1 = *(const float4*)(vr + i + 4);
        float4 b0 = *(const float4*)(bv + i);
        float4 b1 = *(const float4*)(bv + i + 4);
        acc += x0.x*b0.x + x0.y*b0.y + x0.z*b0.z + x0.w*b0.w
             + x1.x*b1.x + x1.y*b1.y + x1.z*b1.z + x1.w*b1.w;
        ushort4 u0, u1;
        u0.x = f2bf(x0.x); u0.y = f2bf(x0.y); u0.z = f2bf(x0.z); u0.w = f2bf(x0.w);
        u1.x = f2bf(x1.x); u1.y = f2bf(x1.y); u1.z = f2bf(x1.z); u1.w = f2bf(x1.w);
        *(ushort4*)(dr + i)     = u0;
        *(ushort4*)(dr + i + 4) = u1;
    }
    __shared__ float sm[256];
    sm[t] = acc;
    __syncthreads();
    for (int s = 128; s > 0; s >>= 1) {
        if (t < s) sm[t] += sm[t + s];
        __syncthreads();
    }
    if (t == 0) vt[b] = sm[0];
}

// ---------------- Kernel B: split-K GEMM, BM=256 BN=64 BK=64, waves 4Mx2N ----------------
// W fp32 -> depth-4 16KB LDS ring via global_load_lds (XOR-swizzled source +
// swizzled read). A (v bf16, XCD-pinned L2-resident) direct global->reg,
// SINGLE-buffered (aC), loaded for t+1 at the END of body t (L2 latency is
// covered by the barrier wait + next body's A-wait; saves 32 VGPRs -> no spill).
// One barrier per body; counted vmcnt, never 0 in the main loop.
//
// Per-wave vmem queue at each wait (oldest first):
//   body-t start (AWAIT):  A(t)8, W(t+1)2            -> vmcnt(2) drains A(t)
//   body-t end   (WWAIT):  W(t+1)2, A(t+1)8, W(t+2)2 -> vmcnt(10) drains W(t+1)
//   tail: body NT-2 WWAIT -> vmcnt(8); body NT-1 AWAIT -> vmcnt(0), no barrier.
// Ring: body t writes slot (t+2)&3, reads slot t&3; all waves are within one
// barrier interval -> disjoint. W cover = 1 full body (~3000cy) >> 900cy HBM.

#define STAGE_W(slot, kt) do {                                                         \
    _Pragma("unroll")                                                                  \
    for (int p_ = 0; p_ < 2; ++p_) {                                                   \
        __builtin_amdgcn_global_load_lds(                                              \
            (const __attribute__((address_space(1))) unsigned int*)(wsrc[p_] + (size_t)(kt) * 64), \
            (__attribute__((address_space(3))) unsigned int*)(&wbuf[(slot)][wldsoff[p_]]), \
            16, 0, 0);                                                                 \
    } } while (0)

#define LOAD_A(dst, kt) do {                                                           \
    _Pragma("unroll")                                                                  \
    for (int m_ = 0; m_ < 4; ++m_)                                                     \
      _Pragma("unroll")                                                                \
      for (int s_ = 0; s_ < 2; ++s_)                                                   \
        dst[m_*2+s_] = *(const bf16x8*)(ap[m_] + (size_t)(kt) * 64 + s_ * 32);         \
    } while (0)

#define COMPUTE(AUSE, T_) do {                                                         \
    const float* wb_ = &wbuf[(T_) & 3][0];                                             \
    _Pragma("unroll")                                                                  \
    for (int s_ = 0; s_ < 2; ++s_) {                                                   \
      bf16x8 bfr[2];                                                                   \
      _Pragma("unroll")                                                                \
      for (int n_ = 0; n_ < 2; ++n_) {                                                 \
        int row_ = wn * 32 + n_ * 16 + lr;                                             \
        int m7_  = row_ & 7;                                                           \
        int g0_  = s_ * 8 + lg * 2;                                                    \
        float4 lo_ = *(const float4*)&wb_[row_ * 64 + (((g0_    ) ^ m7_) << 2)];       \
        float4 hi_ = *(const float4*)&wb_[row_ * 64 + (((g0_ + 1) ^ m7_) << 2)];       \
        bf16x8 t_;                                                                     \
        t_[0]=bfc(lo_.x); t_[1]=bfc(lo_.y); t_[2]=bfc(lo_.z); t_[3]=bfc(lo_.w);        \
        t_[4]=bfc(hi_.x); t_[5]=bfc(hi_.y); t_[6]=bfc(hi_.z); t_[7]=bfc(hi_.w);        \
        bfr[n_] = t_;                                                                  \
      }                                                                                \
      _Pragma("unroll")                                                                \
      for (int m_ = 0; m_ < 4; ++m_)                                                   \
        _Pragma("unroll")                                                              \
        for (int n_ = 0; n_ < 2; ++n_)                                                 \
          acc[m_][n_] = __builtin_amdgcn_mfma_f32_16x16x32_bf16(                       \
              AUSE[m_*2+s_], bfr[n_], acc[m_][n_], 0, 0, 0);                           \
    } } while (0)

#define BODY(T_, AWAIT, ISSA, ISSW, WWAIT, DOBAR) do {                                 \
    asm volatile("s_waitcnt " AWAIT ::: "memory");                                     \
    COMPUTE(aC, T_);                                                                   \
    asm volatile("" ::: "memory");                                                     \
    if (ISSA) LOAD_A(aC, (T_) + 1);                                                    \
    asm volatile("" ::: "memory");                                                     \
    if (ISSW) STAGE_W(((T_) + 2) & 3, (T_) + 2);                                       \
    if (DOBAR) asm volatile("s_waitcnt " WWAIT "\n\ts_barrier" ::: "memory");          \
    } while (0)

__global__ __launch_bounds__(512, 4) void gemm_kernel(
    const __hip_bfloat16* __restrict__ vbf,   // [256][32768] bf16
    const float* __restrict__ W,              // [4096][32768] fp32
    float* __restrict__ part,                 // [KS][256][4096] fp32
    int KS, int NT)                           // NT = (K_/KS)/64, >= 3
{
    __shared__ __align__(16) float wbuf[4][64 * 64];   // 4 x 16 KB ring

    const int tid  = threadIdx.x;
    const int wid  = tid >> 6;
    const int lane = tid & 63;
    const int lr   = lane & 15;   // B-frag n / A-frag row-in-16
    const int lg   = lane >> 4;   // k-granule 0..3

    const int wm = wid & 3;       // wave M group: 64 rows
    const int wn = wid >> 2;      // wave N group: 32 cols

    const int bid   = blockIdx.x;
    const int sidx  = bid % KS;   // k-split; == XCD id when KS==8 (v-slice L2 locality)
    const int ht    = bid / KS;
    const int h0    = ht * 64;
    const int kbase = sidx * (NT * 64);

    // W staging: LDS linear granule (row, g') holds global granule g = g' ^ (row&7)
    const float* wsrc[2];
    int wldsoff[2];
    #pragma unroll
    for (int p = 0; p < 2; ++p) {
        int f   = p * 512 + tid;
        int row = f >> 4;       // 0..63
        int gl  = f & 15;       // linear 16B granule in row
        int g   = gl ^ (row & 7);
        wsrc[p]    = W + (size_t)(h0 + row) * K_ + kbase + g * 4;
        wldsoff[p] = (p * 512 + wid * 64) * 4;   // float idx, wave-uniform base
    }

    // A: this wave owns rows wm*64 .. wm*64+63
    const __hip_bfloat16* ap[4];
    #pragma unroll
    for (int m = 0; m < 4; ++m)
        ap[m] = vbf + (size_t)(wm * 64 + m * 16 + lr) * K_ + kbase + lg * 8;

    f32x4 acc[4][2];
    #pragma unroll
    for (int m = 0; m < 4; ++m)
        #pragma unroll
        for (int n = 0; n < 2; ++n)
            acc[m][n] = (f32x4)(0.0f);

    bf16x8 aC[8];

    // Prologue: A(0), W(0), W(1); wait A(0)+W(0) (W(1) stays in flight); barrier.
    LOAD_A(aC, 0);
    asm volatile("" ::: "memory");
    STAGE_W(0, 0);
    STAGE_W(1, 1);
    asm volatile("s_waitcnt vmcnt(2)\n\ts_barrier" ::: "memory");

    for (int t = 0; t < NT - 2; ++t)
        BODY(t, "vmcnt(2)", true, true, "vmcnt(10)", true);
    BODY(NT - 2, "vmcnt(2)", true,  false, "vmcnt(8)", true);
    BODY(NT - 1, "vmcnt(0)", false, false, "vmcnt(0)", false);

    // Epilogue: C/D layout col=lane&15 (=h), row=(lane>>4)*4+reg (=b)
    float* pout = part + (size_t)sidx * ((size_t)B_ * H_) + h0;
    #pragma unroll
    for (int m = 0; m < 4; ++m)
        #pragma unroll
        for (int n = 0; n < 2; ++n)
            #pragma unroll
            for (int j = 0; j < 4; ++j) {
                int brow = wm * 64 + m * 16 + lg * 4 + j;
                int hcol = wn * 32 + n * 16 + lr;
                pout[(size_t)brow * H_ + hcol] = acc[m][n][j];
            }
}

// ---------------- Kernel C: reduce splits + b_h, softplus, sum over H, + vt ----------------
__global__ __launch_bounds__(256) void reduce_kernel(
    const float* __restrict__ part, const float* __restrict__ bh,
    const float* __restrict__ vt, float* __restrict__ out, int KS)
{
    const int b = blockIdx.x;
    const int t = threadIdx.x;
    float sp = 0.f;
    const float* pb = part + (size_t)b * H_;
    for (int h = t * 4; h < H_; h += 256 * 4) {
        float4 l = *(const float4*)(bh + h);
        for (int s = 0; s < KS; ++s) {
            float4 p = *(const float4*)(pb + (size_t)s * B_ * H_ + h);
            l.x += p.x; l.y += p.y; l.z += p.z; l.w += p.w;
        }
        sp += softplus_f(l.x) + softplus_f(l.y) + softplus_f(l.z) + softplus_f(l.w);
    }
    __shared__ float sm[256];
    sm[t] = sp;
    __syncthreads();
    for (int r = 128; r > 0; r >>= 1) {
        if (t < r) sm[t] += sm[t + r];
        __syncthreads();
    }
    if (t == 0) out[b] = sm[0] + vt[b];
}

extern "C" void kernel_launch(void* const* d_in, const int* in_sizes, int n_in,
                              void* d_out, int out_size, void* d_ws, size_t ws_size,
                              hipStream_t stream)
{
    const float* v  = (const float*)d_in[0];
    const float* W  = (const float*)d_in[1];
    const float* bh = (const float*)d_in[2];
    const float* bv = (const float*)d_in[3];
    float* out = (float*)d_out;

    char* ws = (char*)d_ws;
    const size_t vbf_bytes = (size_t)B_ * K_ * sizeof(__hip_bfloat16);  // 16 MB
    __hip_bfloat16* vbf = (__hip_bfloat16*)ws;

    int KS = 8;                                   // shrink if workspace is small
    while (KS > 1 && vbf_bytes + (size_t)KS * B_ * H_ * 4 + 1024 > ws_size) KS >>= 1;

    float* part = (float*)(ws + vbf_bytes);                                  // KS*4 MB
    float* vt   = (float*)(ws + vbf_bytes + (size_t)KS * B_ * H_ * 4);       // 1 KB

    prep_kernel<<<B_, 256, 0, stream>>>(v, bv, vbf, vt);
    const int NT = (K_ / KS) / 64;                // 64 for KS=8 (>= 3)
    gemm_kernel<<<(H_ / 64) * KS, 512, 0, stream>>>(vbf, W, part, KS, NT);
    reduce_kernel<<<B_, 256, 0, stream>>>(part, bh, vt, out, KS);
}

// Round 8
// 205.497 us; speedup vs baseline: 1.9198x; 1.5510x over previous
//
#include <hip/hip_runtime.h>
#include <hip/hip_bf16.h>
#include <stdint.h>

#define B_ 256
#define H_ 4096
#define K_ 32768   // V*N = 1024*32

typedef __attribute__((ext_vector_type(8))) short bf16x8;
typedef __attribute__((ext_vector_type(4))) float f32x4;

__device__ __forceinline__ unsigned short f2bf(float x) {
    union { float f; unsigned int u; } c; c.f = x;
    unsigned int r = c.u + 0x7FFFu + ((c.u >> 16) & 1u);  // RNE
    return (unsigned short)(r >> 16);
}

__device__ __forceinline__ short bfc(float x) {
    __hip_bfloat16 h = __float2bfloat16(x);
    union { __hip_bfloat16 h; short s; } c; c.h = h;
    return c.s;
}

__device__ __forceinline__ float softplus_f(float x) {
    return fmaxf(x, 0.0f) + log1pf(expf(-fabsf(x)));
}

// ---------------- Kernel A: v fp32->bf16 + vt[b] = dot(v[b,:], b_v) ----------------
__global__ __launch_bounds__(256) void prep_kernel(
    const float* __restrict__ v, const float* __restrict__ bv,
    __hip_bfloat16* __restrict__ vbf, float* __restrict__ vt)
{
    const int b = blockIdx.x;
    const int t = threadIdx.x;
    const float* vr = v + (size_t)b * K_;
    unsigned short* dr = (unsigned short*)(vbf + (size_t)b * K_);
    float acc = 0.f;
    for (int i = t * 8; i < K_; i += 256 * 8) {
        float4 x0 = *(const float4*)(vr + i);
        float4 x1 = *(const float4*)(vr + i + 4);
        float4 b0 = *(const float4*)(bv + i);
        float4 b1 = *(const float4*)(bv + i + 4);
        acc += x0.x*b0.x + x0.y*b0.y + x0.z*b0.z + x0.w*b0.w
             + x1.x*b1.x + x1.y*b1.y + x1.z*b1.z + x1.w*b1.w;
        ushort4 u0, u1;
        u0.x = f2bf(x0.x); u0.y = f2bf(x0.y); u0.z = f2bf(x0.z); u0.w = f2bf(x0.w);
        u1.x = f2bf(x1.x); u1.y = f2bf(x1.y); u1.z = f2bf(x1.z); u1.w = f2bf(x1.w);
        *(ushort4*)(dr + i)     = u0;
        *(ushort4*)(dr + i + 4) = u1;
    }
    __shared__ float sm[256];
    sm[t] = acc;
    __syncthreads();
    for (int s = 128; s > 0; s >>= 1) {
        if (t < s) sm[t] += sm[t + s];
        __syncthreads();
    }
    if (t == 0) vt[b] = sm[0];
}

// ---------------- Kernel B: producer-consumer split-K GEMM ----------------
// BM=256 BN=64 BK=64, KS=8 k-splits (sidx == XCD id -> v slice L2-resident).
// Block = 640 threads: 8 CONSUMER waves (8M x 1N, 32 v-rows each; A bf16
// global->reg double-buffered; 8 ds_read_b128 bf16 + 16 MFMA per body, NO cvt)
// + 2 PRODUCER waves (W fp32 global->reg 2 tiles deep with counted vmcnt ->
// cvt bf16 -> swizzled ds_write_b128 into a depth-4 8KB ring).
// One s_barrier per body; barrier counts identical across roles (NT+1 each).
//
// Ring: producer body j writes slot (j+1)&3 (pre-barrier-j), consumer body t
// reads slot t&3 (post-barrier-(t-1)). Slot s: written at body s-1, read at
// body s, rewritten at body s+3 (after barrier s+2) -> 2-barrier margin.
// Producer vmem queue (8 loads/tile): body j: [tile(j+1) 8, tile(j+2) 8]
//   -> vmcnt(8) drains tile(j+1). Tail body NT-2: vmcnt(0).
// Consumer vmem queue (4 A-loads/tile): [A(t)4, A(t+1)4] -> vmcnt(4); tail 0.

#define NCONS 8

#define LOAD_A(dst, kt) do {                                                           \
    _Pragma("unroll")                                                                  \
    for (int m_ = 0; m_ < 2; ++m_)                                                     \
      _Pragma("unroll")                                                                \
      for (int s_ = 0; s_ < 2; ++s_)                                                   \
        dst[m_*2+s_] = *(const bf16x8*)(ap[m_] + (size_t)(kt) * 64 + s_ * 32);         \
    } while (0)

#define COMPUTE(AUSE, T_) do {                                                         \
    const unsigned short* wb_ = &wtile[(T_) & 3][0];                                   \
    _Pragma("unroll")                                                                  \
    for (int s_ = 0; s_ < 2; ++s_) {                                                   \
      bf16x8 bfr[4];                                                                   \
      _Pragma("unroll")                                                                \
      for (int n_ = 0; n_ < 4; ++n_) {                                                 \
        int row_  = n_ * 16 + lr;                                                      \
        int slot_ = s_ * 4 + lg;                                                       \
        bfr[n_] = *(const bf16x8*)&wb_[row_ * 64 + ((slot_ ^ (row_ & 7)) << 3)];       \
      }                                                                                \
      _Pragma("unroll")                                                                \
      for (int m_ = 0; m_ < 2; ++m_)                                                   \
        _Pragma("unroll")                                                              \
        for (int n_ = 0; n_ < 4; ++n_)                                                 \
          acc[m_][n_] = __builtin_amdgcn_mfma_f32_16x16x32_bf16(                       \
              AUSE[m_*2+s_], bfr[n_], acc[m_][n_], 0, 0, 0);                           \
    } } while (0)

#define CBODY(T_, AUSE, ALOAD, ISSA, VMSTR) do {                                       \
    if (ISSA) LOAD_A(ALOAD, (T_) + 1);                                                 \
    asm volatile("s_waitcnt " VMSTR ::: "memory");                                     \
    COMPUTE(AUSE, T_);                                                                 \
    asm volatile("s_barrier" ::: "memory");                                            \
    } while (0)

#define PLOAD(dst, kt) do {                                                            \
    _Pragma("unroll")                                                                  \
    for (int c_ = 0; c_ < 4; ++c_) {                                                   \
        const float* p_ = wsrc4[c_] + (size_t)(kt) * 64;                               \
        dst[c_*2]   = *(const float4*)p_;                                              \
        dst[c_*2+1] = *(const float4*)(p_ + 4);                                        \
    } } while (0)

#define PWRITE(src, slot_) do {                                                        \
    _Pragma("unroll")                                                                  \
    for (int c_ = 0; c_ < 4; ++c_) {                                                   \
        bf16x8 u_;                                                                     \
        u_[0]=bfc(src[c_*2].x);   u_[1]=bfc(src[c_*2].y);                              \
        u_[2]=bfc(src[c_*2].z);   u_[3]=bfc(src[c_*2].w);                              \
        u_[4]=bfc(src[c_*2+1].x); u_[5]=bfc(src[c_*2+1].y);                            \
        u_[6]=bfc(src[c_*2+1].z); u_[7]=bfc(src[c_*2+1].w);                            \
        *(bf16x8*)&wtile[(slot_)][woff4[c_]] = u_;                                     \
    } } while (0)

// Producer body j: load tile j+2 -> LBUF, drain tile j+1 (vmcnt(8)),
// cvt+write WBUF (tile j+1) -> slot (j+1)&3, lgkmcnt(0), barrier.
#define PBODY(T_, LBUF, WBUF) do {                                                     \
    PLOAD(LBUF, (T_) + 2);                                                             \
    asm volatile("s_waitcnt vmcnt(8)" ::: "memory");                                   \
    PWRITE(WBUF, ((T_) + 1) & 3);                                                      \
    asm volatile("s_waitcnt lgkmcnt(0)\n\ts_barrier" ::: "memory");                    \
    } while (0)

__global__ __launch_bounds__(640, 5) void gemm_kernel(
    const __hip_bfloat16* __restrict__ vbf,   // [256][32768] bf16
    const float* __restrict__ W,              // [4096][32768] fp32
    float* __restrict__ part,                 // [KS][256][4096] fp32
    int KS, int NT)                           // NT = (K_/KS)/64, even, >= 4
{
    __shared__ __align__(16) unsigned short wtile[4][64 * 64];  // 4 x 8 KB bf16 ring

    const int tid  = threadIdx.x;
    const int wid  = tid >> 6;
    const int lane = tid & 63;
    const int lr   = lane & 15;
    const int lg   = lane >> 4;

    const int bid   = blockIdx.x;
    const int sidx  = bid % KS;   // k-split; == XCD id when KS==8
    const int ht    = bid / KS;
    const int h0    = ht * 64;
    const int kbase = sidx * (NT * 64);

    if (wid < NCONS) {
        // ---------------- consumer ----------------
        const __hip_bfloat16* ap[2];
        #pragma unroll
        for (int m = 0; m < 2; ++m)
            ap[m] = vbf + (size_t)(wid * 32 + m * 16 + lr) * K_ + kbase + lg * 8;

        f32x4 acc[2][4];
        #pragma unroll
        for (int m = 0; m < 2; ++m)
            #pragma unroll
            for (int n = 0; n < 4; ++n)
                acc[m][n] = (f32x4)(0.0f);

        bf16x8 aA[4], aB[4];
        LOAD_A(aA, 0);
        asm volatile("s_barrier" ::: "memory");   // prologue barrier

        for (int t = 0; t < NT - 2; t += 2) {
            CBODY(t,     aA, aB, true, "vmcnt(4)");
            CBODY(t + 1, aB, aA, true, "vmcnt(4)");
        }
        CBODY(NT - 2, aA, aB, true,  "vmcnt(4)");
        CBODY(NT - 1, aB, aA, false, "vmcnt(0)");

        // Epilogue: C/D layout col=lane&15 (=h), row=(lane>>4)*4+reg (=b)
        float* pout = part + (size_t)sidx * ((size_t)B_ * H_) + h0;
        #pragma unroll
        for (int m = 0; m < 2; ++m)
            #pragma unroll
            for (int n = 0; n < 4; ++n)
                #pragma unroll
                for (int j = 0; j < 4; ++j) {
                    int brow = wid * 32 + m * 16 + lg * 4 + j;
                    int hcol = n * 16 + lr;
                    pout[(size_t)brow * H_ + hcol] = acc[m][n][j];
                }
    } else {
        // ---------------- producer ----------------
        const int pw = wid - NCONS;   // 0..1
        const float* wsrc4[4];
        int woff4[4];
        #pragma unroll
        for (int c = 0; c < 4; ++c) {
            int idx = c * 128 + pw * 64 + lane;   // 0..511: 8-float chunk id
            int row = idx >> 3;                   // 0..63
            int c8  = idx & 7;                    // 0..7 (16B bf16 granule)
            wsrc4[c] = W + (size_t)(h0 + row) * K_ + kbase + c8 * 8;
            woff4[c] = row * 64 + ((c8 ^ (row & 7)) << 3);
        }

        float4 wgA[8], wgB[8];
        PLOAD(wgA, 0);
        PLOAD(wgB, 1);
        asm volatile("s_waitcnt vmcnt(8)" ::: "memory");   // drain tile 0
        PWRITE(wgA, 0);
        asm volatile("s_waitcnt lgkmcnt(0)\n\ts_barrier" ::: "memory");  // prologue

        for (int t = 0; t < NT - 2; t += 2) {
            PBODY(t,     wgA, wgB);   // load t+2 -> A, write tile t+1 (in B)
            PBODY(t + 1, wgB, wgA);   // load t+3 -> B, write tile t+2 (in A)
        }
        // body NT-2: no load left; drain tile NT-1 (in wgB since NT even)
        asm volatile("s_waitcnt vmcnt(0)" ::: "memory");
        PWRITE(wgB, (NT - 1) & 3);
        asm volatile("s_waitcnt lgkmcnt(0)\n\ts_barrier" ::: "memory");
        // body NT-1: nothing to produce
        asm volatile("s_barrier" ::: "memory");
    }
}

// ---------------- Kernel C: reduce splits + b_h, softplus, sum over H, + vt ----------------
__global__ __launch_bounds__(256) void reduce_kernel(
    const float* __restrict__ part, const float* __restrict__ bh,
    const float* __restrict__ vt, float* __restrict__ out, int KS)
{
    const int b = blockIdx.x;
    const int t = threadIdx.x;
    float sp = 0.f;
    const float* pb = part + (size_t)b * H_;
    for (int h = t * 4; h < H_; h += 256 * 4) {
        float4 l = *(const float4*)(bh + h);
        for (int s = 0; s < KS; ++s) {
            float4 p = *(const float4*)(pb + (size_t)s * B_ * H_ + h);
            l.x += p.x; l.y += p.y; l.z += p.z; l.w += p.w;
        }
        sp += softplus_f(l.x) + softplus_f(l.y) + softplus_f(l.z) + softplus_f(l.w);
    }
    __shared__ float sm[256];
    sm[t] = sp;
    __syncthreads();
    for (int r = 128; r > 0; r >>= 1) {
        if (t < r) sm[t] += sm[t + r];
        __syncthreads();
    }
    if (t == 0) out[b] = sm[0] + vt[b];
}

extern "C" void kernel_launch(void* const* d_in, const int* in_sizes, int n_in,
                              void* d_out, int out_size, void* d_ws, size_t ws_size,
                              hipStream_t stream)
{
    const float* v  = (const float*)d_in[0];
    const float* W  = (const float*)d_in[1];
    const float* bh = (const float*)d_in[2];
    const float* bv = (const float*)d_in[3];
    float* out = (float*)d_out;

    char* ws = (char*)d_ws;
    const size_t vbf_bytes = (size_t)B_ * K_ * sizeof(__hip_bfloat16);  // 16 MB
    __hip_bfloat16* vbf = (__hip_bfloat16*)ws;

    int KS = 8;                                   // shrink if workspace is small
    while (KS > 1 && vbf_bytes + (size_t)KS * B_ * H_ * 4 + 1024 > ws_size) KS >>= 1;

    float* part = (float*)(ws + vbf_bytes);                                  // KS*4 MB
    float* vt   = (float*)(ws + vbf_bytes + (size_t)KS * B_ * H_ * 4);       // 1 KB

    prep_kernel<<<B_, 256, 0, stream>>>(v, bv, vbf, vt);
    const int NT = (K_ / KS) / 64;                // 64 for KS=8 (even, >=4)
    gemm_kernel<<<(H_ / 64) * KS, 640, 0, stream>>>(vbf, W, part, KS, NT);
    reduce_kernel<<<B_, 256, 0, stream>>>(part, bh, vt, out, KS);
}